// Round 4
// baseline (137.441 us; speedup 1.0000x reference)
//
#include <hip/hip_runtime.h>

#define KCLS 21
#define HW (512 * 512)
#define BATCH 8
#define BLKSZ 256
#define NBLK 1024
#define BPI (NBLK / BATCH)            // 128 blocks per image
#define PIXB (HW / BPI)               // 2048 px per block
#define PXT 4
#define ITERS (PIXB / (BLKSZ * PXT))  // 2

// ws layout: u32 done | pad | u64 cnt[NBLK*21] | f32 S[NBLK*21]
// cnt slot pack: inter<<42 | tgt<<21 | aout   (each <= 2048 per block)

__global__ __launch_bounds__(BLKSZ) void dicece_one(
    const float* __restrict__ pr, const int* __restrict__ gt,
    unsigned int* __restrict__ ws_done, unsigned long long* __restrict__ ws_cnt,
    float* __restrict__ ws_S, float* __restrict__ out)
{
    const int t = threadIdx.x;
    const int w = t >> 6, lane = t & 63;
    const int b = blockIdx.x / BPI;
    const int chunk = blockIdx.x - b * BPI;
    const int pix0 = chunk * PIXB;
    const float* __restrict__ pb = pr + (size_t)b * KCLS * HW;
    const int*   __restrict__ gb = gt + (size_t)b * HW;

    // per-lane private accumulators — statically indexed => registers
    unsigned int cnt[KCLS];   // inter<<20 | tgt<<10 | aout (each <= 8 per lane)
    float sS[KCLS];           // sum of (-logp) for gt==k
    #pragma unroll
    for (int k = 0; k < KCLS; ++k) { cnt[k] = 0u; sS[k] = 0.f; }

    #pragma unroll 1
    for (int it = 0; it < ITERS; ++it) {
        const int pix = pix0 + (it * BLKSZ + t) * PXT;

        float x[KCLS][PXT];
        #pragma unroll
        for (int k = 0; k < KCLS; ++k)
            *reinterpret_cast<float4*>(&x[k][0]) =
                *reinterpret_cast<const float4*>(pb + (size_t)k * HW + pix);
        int g[PXT];
        *reinterpret_cast<int4*>(&g[0]) = *reinterpret_cast<const int4*>(gb + pix);

        #pragma unroll
        for (int j = 0; j < PXT; ++j) {
            float m = x[0][j]; int am = 0;
            #pragma unroll
            for (int k = 1; k < KCLS; ++k) if (x[k][j] > m) { m = x[k][j]; am = k; }
            float s = 0.f;
            #pragma unroll
            for (int k = 0; k < KCLS; ++k) s += __expf(x[k][j] - m);
            const int gj = g[j];
            float xg = x[0][j];
            #pragma unroll
            for (int k = 1; k < KCLS; ++k) xg = (k == gj) ? x[k][j] : xg;
            const float mag = (m - xg) + __logf(s);          // = -logp >= 0
            const unsigned int gadd =
                (am == gj) ? ((1u << 20) | (1u << 10)) : (1u << 10);
            #pragma unroll
            for (int k = 0; k < KCLS; ++k) {
                const bool isg = (gj == k);
                const bool isa = (am == k);
                cnt[k] += (isg ? gadd : 0u) + (isa ? 1u : 0u);
                sS[k]  += isg ? mag : 0.f;
            }
        }
    }

    // wave butterfly reduce (no LDS traffic in the hot loop)
    #pragma unroll
    for (int k = 0; k < KCLS; ++k) {
        unsigned int c = cnt[k]; float s = sS[k];
        #pragma unroll
        for (int msk = 1; msk < 64; msk <<= 1) {
            c += __shfl_xor(c, msk);
            s += __shfl_xor(s, msk);
        }
        cnt[k] = c; sS[k] = s;   // wave-uniform; fields <= 512, no overflow
    }

    __shared__ unsigned int sc[4][KCLS];
    __shared__ float ss[4][KCLS];
    __shared__ unsigned int s_win;
    if (lane == 0) {
        #pragma unroll
        for (int k = 0; k < KCLS; ++k) { sc[w][k] = cnt[k]; ss[w][k] = sS[k]; }
    }
    __syncthreads();

    if (t < KCLS) {
        unsigned int i_ = 0u, tg = 0u, ao = 0u; float S = 0.f;
        #pragma unroll
        for (int ww = 0; ww < 4; ++ww) {
            const unsigned int v = sc[ww][t];
            i_ += v >> 20; tg += (v >> 10) & 1023u; ao += v & 1023u;
            S += ss[ww][t];
        }
        // agent-scope stores: visible at device-coherent point (cross-XCD)
        __hip_atomic_store(&ws_cnt[(size_t)blockIdx.x * KCLS + t],
            ((unsigned long long)i_ << 42) | ((unsigned long long)tg << 21) |
            (unsigned long long)ao, __ATOMIC_RELAXED, __HIP_MEMORY_SCOPE_AGENT);
        __hip_atomic_store(&ws_S[(size_t)blockIdx.x * KCLS + t], S,
            __ATOMIC_RELAXED, __HIP_MEMORY_SCOPE_AGENT);
    }
    __threadfence();
    __syncthreads();

    if (t == 0) {
        const unsigned int old = __hip_atomic_fetch_add(
            ws_done, 1u, __ATOMIC_ACQ_REL, __HIP_MEMORY_SCOPE_AGENT);
        s_win = (old == NBLK - 1u) ? 1u : 0u;   // counter memset to 0 each call
    }
    __syncthreads();
    if (s_win == 0u) return;

    // ---- true last block: reduce 1024x21 partials -> scalar ----
    __shared__ float f_dice[BATCH * KCLS], f_tg[BATCH * KCLS], f_S[BATCH * KCLS];
    if (t < BATCH * KCLS) {
        const int bb = t / KCLS, kk = t - bb * KCLS;
        unsigned long long acc = 0ull; float S = 0.f;
        #pragma unroll 8
        for (int sIdx = 0; sIdx < BPI; ++sIdx) {
            const size_t slot = (size_t)(bb * BPI + sIdx) * KCLS + kk;
            acc += __hip_atomic_load(&ws_cnt[slot], __ATOMIC_RELAXED,
                                     __HIP_MEMORY_SCOPE_AGENT);
            S += __hip_atomic_load(&ws_S[slot], __ATOMIC_RELAXED,
                                   __HIP_MEMORY_SCOPE_AGENT);
        }
        const float i_ = (float)(acc >> 42);
        const float tg = (float)((acc >> 21) & 0x1FFFFFull);
        const float ao = (float)(acc & 0x1FFFFFull);
        f_dice[t] = 2.f * i_ / (ao + tg + 1e-10f);
        f_tg[t] = tg;
        f_S[t] = S;
    }
    __syncthreads();
    if (t >= 64) return;

    float wgt = 0.f, Nk = 0.f, Sk = 0.f;
    if (t < KCLS) {
        float dsum = 0.f;
        #pragma unroll
        for (int bb = 0; bb < BATCH; ++bb) {
            dsum += f_dice[bb * KCLS + t];
            Nk   += f_tg[bb * KCLS + t];
            Sk   += f_S[bb * KCLS + t];
        }
        wgt = 1.f - dsum * 0.125f;
    }
    float num = wgt * Sk, den = wgt * Nk, wsum = wgt;
    #pragma unroll
    for (int off = 32; off > 0; off >>= 1) {
        num += __shfl_down(num, off);
        den += __shfl_down(den, off);
        wsum += __shfl_down(wsum, off);
    }
    // loss = mean(weight) + (sum w*(-logp)) / (sum w*N)
    if (t == 0) out[0] = wsum * (1.f / (float)KCLS) + num / den;
}

extern "C" void kernel_launch(void* const* d_in, const int* in_sizes, int n_in,
                              void* d_out, int out_size, void* d_ws, size_t ws_size,
                              hipStream_t stream) {
    const float* pr = (const float*)d_in[0];
    const int*   gt = (const int*)d_in[1];
    float* out = (float*)d_out;

    unsigned int*       ws_done = (unsigned int*)d_ws;
    unsigned long long* ws_cnt  = (unsigned long long*)((char*)d_ws + 8);
    float*              ws_S    = (float*)(ws_cnt + (size_t)NBLK * KCLS);

    hipMemsetAsync(ws_done, 0, 4, stream);   // exact last-block election per call
    dicece_one<<<NBLK, BLKSZ, 0, stream>>>(pr, gt, ws_done, ws_cnt, ws_S, out);
}